// Round 3
// baseline (607.249 us; speedup 1.0000x reference)
//
#include <hip/hip_runtime.h>
#include <math.h>

#define CDIM 256
#define LSEQ 8192
#define BATCH 8
#define MTOT (BATCH * LSEQ)
#define PADROWS 8208           // 8 + 8192 + 8 per batch
#define PAD0 8

typedef unsigned short ushort_t;
typedef unsigned int uint_t;

typedef __bf16 bf16x8 __attribute__((ext_vector_type(8)));
typedef float f32x4 __attribute__((ext_vector_type(4)));

__device__ __forceinline__ ushort_t f2bf(float f) {
    union { float f; uint_t u; } v; v.f = f;
    uint_t u = v.u;
    return (ushort_t)((u + 0x7FFFu + ((u >> 16) & 1u)) >> 16);  // RNE
}
__device__ __forceinline__ float bf2f(ushort_t h) {
    union { uint_t u; float f; } v; v.u = ((uint_t)h) << 16;
    return v.f;
}
__device__ __forceinline__ float gelu_exact(float x) {
    return 0.5f * x * (1.0f + erff(x * 0.70710678118654752440f));
}

// async global(16B/lane) -> LDS (wave-uniform base + lane*16)
__device__ __forceinline__ void gload16(const ushort_t* g, ushort_t* lds) {
    __builtin_amdgcn_global_load_lds(
        reinterpret_cast<__attribute__((address_space(1))) uint_t*>(
            reinterpret_cast<uintptr_t>(g)),
        reinterpret_cast<__attribute__((address_space(3))) uint_t*>(
            reinterpret_cast<uintptr_t>(lds)),
        16, 0, 0);
}

// ---------------- fp32 -> bf16 convert ----------------
__global__ __launch_bounds__(256) void cvt_f32_bf16(const float* __restrict__ in,
                                                    ushort_t* __restrict__ out) {
    int i = blockIdx.x * 256 + threadIdx.x;
    float4 v = ((const float4*)in)[i];
    ushort4 o = { f2bf(v.x), f2bf(v.y), f2bf(v.z), f2bf(v.w) };
    ((ushort4*)out)[i] = o;
}

// ---------------- transpose + convert: out[n*K+k] = bf16(in[k*ldin+col0+n]) ----------------
__global__ __launch_bounds__(256) void transpose_cvt(const float* __restrict__ in,
                                                     ushort_t* __restrict__ out,
                                                     int K, int N, int ldin, int col0) {
    __shared__ float t[32][33];
    int k0 = blockIdx.x * 32, n0 = blockIdx.y * 32;
    int tx = threadIdx.x, ty = threadIdx.y;   // (32,8)
    #pragma unroll
    for (int i = 0; i < 4; i++) {
        int k = k0 + ty + i * 8;
        t[ty + i * 8][tx] = in[(size_t)k * ldin + col0 + n0 + tx];
    }
    __syncthreads();
    #pragma unroll
    for (int i = 0; i < 4; i++) {
        int n = n0 + ty + i * 8;
        out[(size_t)n * K + k0 + tx] = f2bf(t[tx][ty + i * 8]);
    }
}

// ---------------- zero the guard bands of a ctx_pad buffer ----------------
__global__ __launch_bounds__(256) void zero_guards(ushort_t* __restrict__ ctx_pad) {
    int i = blockIdx.x * 256 + threadIdx.x;   // 8*16*256 = 32768
    int c = i & 255;
    int r = (i >> 8) & 15;
    int b = i >> 12;
    int row = b * PADROWS + ((r < 8) ? r : (PADROWS - 16 + r));
    ctx_pad[(size_t)row * CDIM + c] = 0;
}

// ---------------- generic MFMA GEMM (m97 structure): 128x128 tile ----------------
// MODE 0: C[row*256+col] = acc + bias  (fp32 out)
// MODE 1: fea: col<256 -> q_bf(bf16) ; col>=256 -> ctx_pad (padded rows, bf16)
// MODE 2: qc in-place: q_out[idx] = bf16(bf2f(q_out[idx]) * (acc+bias))
template <int MODE>
__global__ __launch_bounds__(256) void gemm_bf16(
    const ushort_t* __restrict__ A, const ushort_t* __restrict__ BT,
    const float* __restrict__ bias,
    float* __restrict__ C, ushort_t* __restrict__ q_out, ushort_t* __restrict__ ctx_pad,
    int Ktot)
{
    __shared__ __align__(16) ushort_t As[128 * 32];
    __shared__ __align__(16) ushort_t Bs[128 * 32];
    int tid = threadIdx.x;
    int w = tid >> 6, l = tid & 63;
    int bn = blockIdx.x * 128;
    int by = blockIdx.y;
    long arow0 = (long)by * 128;
    int crow0 = by * 128;

    int wr = w >> 1, wc = w & 1;
    int lr = l & 15, lk = (l >> 4) * 8;
    int sr = l >> 2;
    int sc = (l & 3) * 8;

    f32x4 acc[4][4] = {};

    int nsteps = Ktot >> 5;
    for (int kt = 0; kt < nsteps; ++kt) {
        int k0 = kt << 5;
        #pragma unroll
        for (int jj = 0; jj < 2; ++jj) {
            int j = w * 2 + jj;
            int r = j * 16 + sr;
            gload16(A + (arow0 + r) * CDIM + (k0 + sc), &As[j * 512]);
            gload16(BT + (long)(bn + r) * Ktot + (k0 + sc), &Bs[j * 512]);
        }
        __syncthreads();
        bf16x8 av[4], bv[4];
        #pragma unroll
        for (int m = 0; m < 4; ++m)
            av[m] = *reinterpret_cast<const bf16x8*>(&As[(wr * 64 + m * 16 + lr) * 32 + lk]);
        #pragma unroll
        for (int n = 0; n < 4; ++n)
            bv[n] = *reinterpret_cast<const bf16x8*>(&Bs[(wc * 64 + n * 16 + lr) * 32 + lk]);
        #pragma unroll
        for (int m = 0; m < 4; ++m)
            #pragma unroll
            for (int n = 0; n < 4; ++n)
                acc[m][n] = __builtin_amdgcn_mfma_f32_16x16x32_bf16(av[m], bv[n], acc[m][n], 0, 0, 0);
        __syncthreads();
    }

    int rbase = (l >> 4) * 4;
    #pragma unroll
    for (int n = 0; n < 4; ++n) {
        int col = bn + wc * 64 + n * 16 + lr;
        float bia = bias[col];
        #pragma unroll
        for (int m = 0; m < 4; ++m) {
            int rowb = crow0 + wr * 64 + m * 16 + rbase;
            #pragma unroll
            for (int r = 0; r < 4; ++r) {
                float v = acc[m][n][r] + bia;
                int row = rowb + r;
                if (MODE == 0) {
                    C[(size_t)row * CDIM + col] = v;
                } else if (MODE == 1) {
                    if (col < CDIM) {
                        q_out[(size_t)row * CDIM + col] = f2bf(v);
                    } else {
                        int bb = row >> 13, tb = row & (LSEQ - 1);
                        ctx_pad[((size_t)bb * PADROWS + PAD0 + tb) * CDIM + (col - CDIM)] = f2bf(v);
                    }
                } else {
                    size_t idx = (size_t)row * CDIM + col;
                    q_out[idx] = f2bf(bf2f(q_out[idx]) * v);
                }
            }
        }
    }
}

// ---------------- fused conv GEMM (BM=128, BN=256) + GELU + LN + gated accumulate ----------------
// A: ctx_pad_in (padded bf16), BT: [256][Ktot] bf16. 512 threads / 8 waves.
// Epilogue: g=gelu(acc+bias); LN over 256 cols; write ctx_pad_out (bf16) and
// ctx_all (fp32, d_out): level0 store y*gate else +=.
__global__ __launch_bounds__(512) void conv_fused(
    const ushort_t* __restrict__ A, const ushort_t* __restrict__ BT,
    const float* __restrict__ bias,
    const float* __restrict__ lng, const float* __restrict__ lnb,
    const float* __restrict__ gates,
    ushort_t* __restrict__ ctx_out, float* __restrict__ ctx_all,
    int Ktot, int koff, int level)
{
    __shared__ __align__(16) ushort_t As[128 * 32];
    __shared__ __align__(16) ushort_t Bs[256 * 32];
    __shared__ float rs[128][2], rq[128][2];

    int tid = threadIdx.x;
    int w = tid >> 6, l = tid & 63;
    int by = blockIdx.x;
    int b = by >> 6;                 // 64 tiles per batch
    int tloc = (by & 63) * 128;
    long arow0 = (long)b * PADROWS + PAD0 + tloc;

    int wr = w >> 1;                 // 0..3 : rows wr*32..+31
    int wc = w & 1;                  // 0..1 : cols wc*128..+127
    int lr = l & 15, lk = (l >> 4) * 8;

    f32x4 acc[2][8] = {};

    int nsteps = Ktot >> 5;
    for (int kt = 0; kt < nsteps; ++kt) {
        int k0 = kt << 5;
        #pragma unroll
        for (int jj = 0; jj < 3; ++jj) {
            int j = w * 3 + jj;      // 24 chunks: 0..7 A, 8..23 B
            if (j < 8) {
                int r = j * 16 + (l >> 2);
                gload16(A + (arow0 + r) * CDIM + (koff + k0 + (l & 3) * 8), &As[j * 512]);
            } else {
                int rB = (j - 8) * 16 + (l >> 2);
                gload16(BT + (long)rB * Ktot + (k0 + (l & 3) * 8), &Bs[(j - 8) * 512]);
            }
        }
        __syncthreads();
        bf16x8 av[2], bv[8];
        #pragma unroll
        for (int m = 0; m < 2; ++m)
            av[m] = *reinterpret_cast<const bf16x8*>(&As[(wr * 32 + m * 16 + lr) * 32 + lk]);
        #pragma unroll
        for (int n = 0; n < 8; ++n)
            bv[n] = *reinterpret_cast<const bf16x8*>(&Bs[(wc * 128 + n * 16 + lr) * 32 + lk]);
        #pragma unroll
        for (int m = 0; m < 2; ++m)
            #pragma unroll
            for (int n = 0; n < 8; ++n)
                acc[m][n] = __builtin_amdgcn_mfma_f32_16x16x32_bf16(av[m], bv[n], acc[m][n], 0, 0, 0);
        __syncthreads();
    }

    // ---- epilogue: bias + GELU + row stats ----
    int rbase = (l >> 4) * 4;
    float bias_c[8], lng_c[8], lnb_c[8];
    #pragma unroll
    for (int n = 0; n < 8; ++n) {
        int col = wc * 128 + n * 16 + lr;
        bias_c[n] = bias[col];
        lng_c[n] = lng[col];
        lnb_c[n] = lnb[col];
    }
    #pragma unroll
    for (int m = 0; m < 2; ++m) {
        #pragma unroll
        for (int r = 0; r < 4; ++r) {
            float s = 0.0f, sq = 0.0f;
            #pragma unroll
            for (int n = 0; n < 8; ++n) {
                float v = acc[m][n][r] + bias_c[n];
                v = gelu_exact(v);
                acc[m][n][r] = v;
                s += v; sq += v * v;
            }
            s += __shfl_xor(s, 1);  sq += __shfl_xor(sq, 1);
            s += __shfl_xor(s, 2);  sq += __shfl_xor(sq, 2);
            s += __shfl_xor(s, 4);  sq += __shfl_xor(sq, 4);
            s += __shfl_xor(s, 8);  sq += __shfl_xor(sq, 8);
            if (lr == 0) {
                int rl = wr * 32 + m * 16 + rbase + r;
                rs[rl][wc] = s;
                rq[rl][wc] = sq;
            }
        }
    }
    __syncthreads();
    #pragma unroll
    for (int m = 0; m < 2; ++m) {
        #pragma unroll
        for (int r = 0; r < 4; ++r) {
            int rl = wr * 32 + m * 16 + rbase + r;
            float mean = (rs[rl][0] + rs[rl][1]) * (1.0f / 256.0f);
            float var = (rq[rl][0] + rq[rl][1]) * (1.0f / 256.0f) - mean * mean;
            float inv = rsqrtf(var + 1e-3f);
            long grow = (long)by * 128 + rl;
            int bb = (int)(grow >> 13), tb = (int)(grow & (LSEQ - 1));
            float gate = gates[grow * 4 + level];
            ushort_t* cp = ctx_out + ((size_t)bb * PADROWS + PAD0 + tb) * CDIM;
            float* ca = ctx_all + (size_t)grow * CDIM;
            #pragma unroll
            for (int n = 0; n < 8; ++n) {
                int col = wc * 128 + n * 16 + lr;
                float y = (acc[m][n][r] - mean) * inv * lng_c[n] + lnb_c[n];
                cp[col] = f2bf(y);
                if (level == 0) ca[col] = y * gate;
                else            ca[col] += y * gate;
            }
        }
    }
}

// ---------------- gates sliver ----------------
__global__ __launch_bounds__(256) void gates_kernel(const float* __restrict__ x,
                                                    const float* __restrict__ f_w,
                                                    const float* __restrict__ f_b,
                                                    float* __restrict__ gates) {
    __shared__ float fcol[256][4];
    int tid = threadIdx.x;
    #pragma unroll
    for (int j = 0; j < 4; ++j) fcol[tid][j] = f_w[(size_t)tid * 516 + 512 + j];
    __syncthreads();
    int w = tid >> 6, l = tid & 63;
    int t = blockIdx.x * 4 + w;
    float4 xv = ((const float4*)(x + (size_t)t * CDIM))[l];
    int c = l * 4;
    float a[4];
    #pragma unroll
    for (int j = 0; j < 4; ++j)
        a[j] = xv.x * fcol[c][j] + xv.y * fcol[c + 1][j] + xv.z * fcol[c + 2][j] + xv.w * fcol[c + 3][j];
    #pragma unroll
    for (int off = 32; off >= 1; off >>= 1)
        #pragma unroll
        for (int j = 0; j < 4; ++j) a[j] += __shfl_xor(a[j], off);
    if (l == 0) {
        #pragma unroll
        for (int j = 0; j < 4; ++j) gates[(size_t)t * 4 + j] = a[j] + f_b[512 + j];
    }
}

// ---------------- column mean over L (two stage), input bf16 padded ----------------
__global__ __launch_bounds__(256) void col_mean_partial(const ushort_t* __restrict__ ctx_pad,
                                                        float* __restrict__ partial) {
    int b = blockIdx.x, chunk = blockIdx.y, c = threadIdx.x;
    const ushort_t* base = ctx_pad + ((size_t)b * PADROWS + PAD0 + chunk * 256) * CDIM + c;
    float s = 0.0f;
    for (int r = 0; r < 256; ++r) s += bf2f(base[(size_t)r * CDIM]);
    partial[((size_t)b * 32 + chunk) * CDIM + c] = s;
}

__global__ __launch_bounds__(256) void col_mean_final(const float* __restrict__ partial,
                                                      float* __restrict__ meanv) {
    int b = blockIdx.x, c = threadIdx.x;
    float s = 0.0f;
    for (int i = 0; i < 32; ++i) s += partial[((size_t)b * 32 + i) * CDIM + c];
    meanv[b * CDIM + c] = s * (1.0f / (float)LSEQ);
}

// ---------------- A_bf = bf16(ctx_all + meanv[b]*gate3) ----------------
__global__ __launch_bounds__(256) void finalize_A(const float* __restrict__ ctx_all,
                                                  const float* __restrict__ meanv,
                                                  const float* __restrict__ gates,
                                                  ushort_t* __restrict__ A_bf) {
    int i = blockIdx.x * 256 + threadIdx.x;
    int t = i >> 6;
    int c4 = (i & 63) * 4;
    int b = t >> 13;
    float g3 = gates[(size_t)t * 4 + 3];
    float4 v = ((const float4*)ctx_all)[i];
    const float* mv = meanv + b * CDIM + c4;
    v.x += mv[0] * g3; v.y += mv[1] * g3; v.z += mv[2] * g3; v.w += mv[3] * g3;
    ushort4 o = { f2bf(v.x), f2bf(v.y), f2bf(v.z), f2bf(v.w) };
    ((ushort4*)A_bf)[i] = o;
}

extern "C" void kernel_launch(void* const* d_in, const int* in_sizes, int n_in,
                              void* d_out, int out_size, void* d_ws, size_t ws_size,
                              hipStream_t stream) {
    const float* x      = (const float*)d_in[0];
    const float* f_w    = (const float*)d_in[1];
    const float* f_b    = (const float*)d_in[2];
    const float* h_w    = (const float*)d_in[3];
    const float* h_b    = (const float*)d_in[4];
    const float* proj_w = (const float*)d_in[5];
    const float* proj_b = (const float*)d_in[6];
    const float* conv_w[3] = { (const float*)d_in[7],  (const float*)d_in[11], (const float*)d_in[15] };
    const float* conv_b[3] = { (const float*)d_in[8],  (const float*)d_in[12], (const float*)d_in[16] };
    const float* ln_g[3]   = { (const float*)d_in[9],  (const float*)d_in[13], (const float*)d_in[17] };
    const float* ln_b[3]   = { (const float*)d_in[10], (const float*)d_in[14], (const float*)d_in[18] };

    const size_t MC = (size_t)MTOT * CDIM;
    char* w = (char*)d_ws;
    ushort_t* x_bf    = (ushort_t*)w;  w += MC * 2;
    ushort_t* q_bf    = (ushort_t*)w;  w += MC * 2;
    ushort_t* ctx_padA = (ushort_t*)w; w += (size_t)BATCH * PADROWS * CDIM * 2;
    ushort_t* ctx_padB = (ushort_t*)w; w += (size_t)BATCH * PADROWS * CDIM * 2;
    float* gates      = (float*)w;     w += (size_t)MTOT * 4 * 4;
    float* partial    = (float*)w;     w += (size_t)8 * 32 * CDIM * 4;
    float* meanv      = (float*)w;     w += (size_t)8 * CDIM * 4;
    ushort_t* f_wT    = (ushort_t*)w;  w += (size_t)512 * 256 * 2;
    ushort_t* convT0  = (ushort_t*)w;  w += (size_t)768 * 256 * 2;
    ushort_t* convT1  = (ushort_t*)w;  w += (size_t)1280 * 256 * 2;
    ushort_t* convT2  = (ushort_t*)w;  w += (size_t)1792 * 256 * 2;
    ushort_t* h_wT    = (ushort_t*)w;  w += (size_t)256 * 256 * 2;
    ushort_t* proj_wT = (ushort_t*)w;  w += (size_t)256 * 256 * 2;
    ushort_t* A_bf = x_bf;             // reuse (x_bf consumed after fea gemm)
    float* ctx_all = (float*)d_out;

    dim3 blk(256);
    dim3 t8(32, 8);

    // weight prep + x conversion
    cvt_f32_bf16<<<dim3(MC / 4 / 256), blk, 0, stream>>>(x, x_bf);
    transpose_cvt<<<dim3(8, 16), t8, 0, stream>>>(f_w, f_wT, 256, 512, 516, 0);
    transpose_cvt<<<dim3(24, 8), t8, 0, stream>>>(conv_w[0], convT0, 768, 256, 256, 0);
    transpose_cvt<<<dim3(40, 8), t8, 0, stream>>>(conv_w[1], convT1, 1280, 256, 256, 0);
    transpose_cvt<<<dim3(56, 8), t8, 0, stream>>>(conv_w[2], convT2, 1792, 256, 256, 0);
    transpose_cvt<<<dim3(8, 8), t8, 0, stream>>>(h_w, h_wT, 256, 256, 256, 0);
    transpose_cvt<<<dim3(8, 8), t8, 0, stream>>>(proj_w, proj_wT, 256, 256, 256, 0);
    zero_guards<<<dim3(128), blk, 0, stream>>>(ctx_padA);
    zero_guards<<<dim3(128), blk, 0, stream>>>(ctx_padB);

    // feature GEMM (q + ctx) and gates sliver
    gemm_bf16<1><<<dim3(4, 512), blk, 0, stream>>>(x_bf, f_wT, f_b,
        nullptr, q_bf, ctx_padA, 256);
    gates_kernel<<<dim3(MTOT / 4), blk, 0, stream>>>(x, f_w, f_b, gates);

    // three fused conv+GELU+LN+gate levels (ping-pong A->B->A->B)
    conv_fused<<<dim3(512), dim3(512), 0, stream>>>(ctx_padA, convT0, conv_b[0],
        ln_g[0], ln_b[0], gates, ctx_padB, ctx_all, 768, -256, 0);
    conv_fused<<<dim3(512), dim3(512), 0, stream>>>(ctx_padB, convT1, conv_b[1],
        ln_g[1], ln_b[1], gates, ctx_padA, ctx_all, 1280, -512, 1);
    conv_fused<<<dim3(512), dim3(512), 0, stream>>>(ctx_padA, convT2, conv_b[2],
        ln_g[2], ln_b[2], gates, ctx_padB, ctx_all, 1792, -768, 2);

    // global context mean (final ctx is ctx_padB)
    col_mean_partial<<<dim3(BATCH, 32), blk, 0, stream>>>(ctx_padB, partial);
    col_mean_final<<<dim3(BATCH), blk, 0, stream>>>(partial, meanv);

    // h GEMM input: ctx_all + mean*gate3 (bf16)
    finalize_A<<<dim3(MC / 4 / 256), blk, 0, stream>>>(ctx_all, meanv, gates, A_bf);
    // h GEMM with fused q .* (.) epilogue: q_bf <- bf16(q_bf * ctxh)
    gemm_bf16<2><<<dim3(2, 512), blk, 0, stream>>>(A_bf, h_wT, h_b,
        nullptr, q_bf, nullptr, 256);
    // final projection: qc @ proj_w -> d_out (fp32)
    gemm_bf16<0><<<dim3(2, 512), blk, 0, stream>>>(q_bf, proj_wT, proj_b,
        (float*)d_out, nullptr, nullptr, 256);
}

// Round 4
// 448.130 us; speedup vs baseline: 1.3551x; 1.3551x over previous
//
#include <hip/hip_runtime.h>
#include <math.h>

#define CDIM 256
#define LSEQ 8192
#define BATCH 8
#define MTOT (BATCH * LSEQ)
#define PADROWS 8208           // 8 + 8192 + 8 per batch
#define PAD0 8

typedef unsigned short ushort_t;
typedef unsigned int uint_t;

typedef __bf16 bf16x8 __attribute__((ext_vector_type(8)));
typedef float f32x4 __attribute__((ext_vector_type(4)));

__device__ __forceinline__ ushort_t f2bf(float f) {
    union { float f; uint_t u; } v; v.f = f;
    uint_t u = v.u;
    return (ushort_t)((u + 0x7FFFu + ((u >> 16) & 1u)) >> 16);  // RNE
}
__device__ __forceinline__ float bf2f(ushort_t h) {
    union { uint_t u; float f; } v; v.u = ((uint_t)h) << 16;
    return v.f;
}
__device__ __forceinline__ float gelu_exact(float x) {
    return 0.5f * x * (1.0f + erff(x * 0.70710678118654752440f));
}

// async global(16B/lane) -> LDS (wave-uniform base + lane*16)
__device__ __forceinline__ void gload16(const ushort_t* g, ushort_t* lds) {
    __builtin_amdgcn_global_load_lds(
        reinterpret_cast<__attribute__((address_space(1))) uint_t*>(
            reinterpret_cast<uintptr_t>(g)),
        reinterpret_cast<__attribute__((address_space(3))) uint_t*>(
            reinterpret_cast<uintptr_t>(lds)),
        16, 0, 0);
}

// ---------------- fp32 -> bf16 convert ----------------
__global__ __launch_bounds__(256) void cvt_f32_bf16(const float* __restrict__ in,
                                                    ushort_t* __restrict__ out) {
    int i = blockIdx.x * 256 + threadIdx.x;
    float4 v = ((const float4*)in)[i];
    ushort4 o = { f2bf(v.x), f2bf(v.y), f2bf(v.z), f2bf(v.w) };
    ((ushort4*)out)[i] = o;
}

// ---------------- transpose + convert: out[n*K+k] = bf16(in[k*ldin+col0+n]) ----------------
__global__ __launch_bounds__(256) void transpose_cvt(const float* __restrict__ in,
                                                     ushort_t* __restrict__ out,
                                                     int K, int N, int ldin, int col0) {
    __shared__ float t[32][33];
    int k0 = blockIdx.x * 32, n0 = blockIdx.y * 32;
    int tx = threadIdx.x, ty = threadIdx.y;   // (32,8)
    #pragma unroll
    for (int i = 0; i < 4; i++) {
        int k = k0 + ty + i * 8;
        t[ty + i * 8][tx] = in[(size_t)k * ldin + col0 + n0 + tx];
    }
    __syncthreads();
    #pragma unroll
    for (int i = 0; i < 4; i++) {
        int n = n0 + ty + i * 8;
        out[(size_t)n * K + k0 + tx] = f2bf(t[tx][ty + i * 8]);
    }
}

// ---------------- zero the guard bands of a ctx_pad buffer ----------------
__global__ __launch_bounds__(256) void zero_guards(ushort_t* __restrict__ ctx_pad) {
    int i = blockIdx.x * 256 + threadIdx.x;   // 8*16*256 = 32768
    int c = i & 255;
    int r = (i >> 8) & 15;
    int b = i >> 12;
    int row = b * PADROWS + ((r < 8) ? r : (PADROWS - 16 + r));
    ctx_pad[(size_t)row * CDIM + c] = 0;
}

// ---------------- generic MFMA GEMM (m97 structure): 128x128 tile ----------------
// MODE 0: C[row*256+col] = acc + bias  (fp32 out)
// MODE 1: fea: col<256 -> q_bf(bf16) ; col>=256 -> ctx_pad (padded rows, bf16)
// MODE 2: qc in-place: q_out[idx] = bf16(bf2f(q_out[idx]) * (acc+bias))
template <int MODE>
__global__ __launch_bounds__(256) void gemm_bf16(
    const ushort_t* __restrict__ A, const ushort_t* __restrict__ BT,
    const float* __restrict__ bias,
    float* __restrict__ C, ushort_t* __restrict__ q_out, ushort_t* __restrict__ ctx_pad,
    int Ktot)
{
    __shared__ __align__(16) ushort_t As[128 * 32];
    __shared__ __align__(16) ushort_t Bs[128 * 32];
    int tid = threadIdx.x;
    int w = tid >> 6, l = tid & 63;
    int bn = blockIdx.x * 128;
    int by = blockIdx.y;
    long arow0 = (long)by * 128;
    int crow0 = by * 128;

    int wr = w >> 1, wc = w & 1;
    int lr = l & 15, lk = (l >> 4) * 8;
    int sr = l >> 2;
    int sc = (l & 3) * 8;

    f32x4 acc[4][4] = {};

    int nsteps = Ktot >> 5;
    for (int kt = 0; kt < nsteps; ++kt) {
        int k0 = kt << 5;
        #pragma unroll
        for (int jj = 0; jj < 2; ++jj) {
            int j = w * 2 + jj;
            int r = j * 16 + sr;
            gload16(A + (arow0 + r) * CDIM + (k0 + sc), &As[j * 512]);
            gload16(BT + (long)(bn + r) * Ktot + (k0 + sc), &Bs[j * 512]);
        }
        __syncthreads();
        bf16x8 av[4], bv[4];
        #pragma unroll
        for (int m = 0; m < 4; ++m)
            av[m] = *reinterpret_cast<const bf16x8*>(&As[(wr * 64 + m * 16 + lr) * 32 + lk]);
        #pragma unroll
        for (int n = 0; n < 4; ++n)
            bv[n] = *reinterpret_cast<const bf16x8*>(&Bs[(wc * 64 + n * 16 + lr) * 32 + lk]);
        #pragma unroll
        for (int m = 0; m < 4; ++m)
            #pragma unroll
            for (int n = 0; n < 4; ++n)
                acc[m][n] = __builtin_amdgcn_mfma_f32_16x16x32_bf16(av[m], bv[n], acc[m][n], 0, 0, 0);
        __syncthreads();
    }

    int rbase = (l >> 4) * 4;
    #pragma unroll
    for (int n = 0; n < 4; ++n) {
        int col = bn + wc * 64 + n * 16 + lr;
        float bia = bias[col];
        #pragma unroll
        for (int m = 0; m < 4; ++m) {
            int rowb = crow0 + wr * 64 + m * 16 + rbase;
            #pragma unroll
            for (int r = 0; r < 4; ++r) {
                float v = acc[m][n][r] + bia;
                int row = rowb + r;
                if (MODE == 0) {
                    C[(size_t)row * CDIM + col] = v;
                } else if (MODE == 1) {
                    if (col < CDIM) {
                        q_out[(size_t)row * CDIM + col] = f2bf(v);
                    } else {
                        int bb = row >> 13, tb = row & (LSEQ - 1);
                        ctx_pad[((size_t)bb * PADROWS + PAD0 + tb) * CDIM + (col - CDIM)] = f2bf(v);
                    }
                } else {
                    size_t idx = (size_t)row * CDIM + col;
                    q_out[idx] = f2bf(bf2f(q_out[idx]) * v);
                }
            }
        }
    }
}

// ---------------- halo-LDS fused conv: BM=128, BN=256, 512 thr, 1 block/CU ----------------
// A halo (144 rows x 256 ch bf16 = 72KB) staged ONCE, XOR-swizzled.
// B [256][Ktot] in 16KB chunks, double-buffered, XOR-swizzled.
// Epilogue: bias + GELU + LayerNorm -> ctx_out (bf16 padded). No fp32 RMW.
__global__ __launch_bounds__(512) void conv_fused(
    const ushort_t* __restrict__ A, const ushort_t* __restrict__ BT,
    const float* __restrict__ bias,
    const float* __restrict__ lng, const float* __restrict__ lnb,
    ushort_t* __restrict__ ctx_out, int KW, int Ktot)
{
    __shared__ __align__(16) ushort_t As[144 * 256];    // 73728 B
    __shared__ __align__(16) ushort_t Bs[2][256 * 32];  // 2 x 16384 B
    __shared__ float rs[128][4], rq[128][4];            // 4096 B

    int tid = threadIdx.x;
    int w = tid >> 6, l = tid & 63;
    int by = blockIdx.x;              // 512 blocks: 64 tiles/batch
    int b = by >> 6;
    int tloc = (by & 63) << 7;
    const ushort_t* Arow0 = A + ((size_t)b * PADROWS + PAD0 + tloc - 8) * CDIM;

    int wr = w >> 2;                  // 0..1 : rows wr*64..+63
    int wc = w & 3;                   // 0..3 : cols wc*64..+63
    int lr = l & 15, lk = (l >> 4) * 8;
    int quad = l >> 4;

    // ---- stage A halo once: 144 rows * 32 chunks = 4608 chunks (9/thread) ----
    #pragma unroll
    for (int i = 0; i < 9; ++i) {
        int o = tid + i * 512;
        int row = o >> 5, cp = o & 31;
        int cg = cp ^ (row & 7);       // pre-swizzled source (involution)
        gload16(Arow0 + (size_t)row * CDIM + cg * 8, &As[(w * 64 + i * 512) * 8]);
    }
    // ---- stage B chunk 0 into buf 0 ----
    {
        #pragma unroll
        for (int i = 0; i < 2; ++i) {
            int o = tid + i * 512;
            int n = o >> 2, cp = o & 3;
            int cg = cp ^ ((n >> 1) & 3);
            gload16(BT + (size_t)n * Ktot + cg * 8, &Bs[0][(w * 64 + i * 512) * 8]);
        }
    }
    __syncthreads();   // drains vmcnt+lgkm

    int P = KW >> 1;
    int hoff = 8 - P;
    f32x4 acc[4][4] = {};
    int nIt = KW * 8;

    for (int it = 0; it < nIt; ++it) {
        int nx = it + 1;
        if (nx < nIt) {
            int tapn = nx >> 3, c0n = nx & 7;
            #pragma unroll
            for (int i = 0; i < 2; ++i) {
                int o = tid + i * 512;
                int n = o >> 2, cp = o & 3;
                int cg = cp ^ ((n >> 1) & 3);
                gload16(BT + (size_t)n * Ktot + (tapn * 256 + c0n * 32 + cg * 8),
                        &Bs[nx & 1][(w * 64 + i * 512) * 8]);
            }
        }
        int tap = it >> 3, c0 = it & 7;
        int buf = it & 1;
        bf16x8 av[4], bv[4];
        #pragma unroll
        for (int m = 0; m < 4; ++m) {
            int row = wr * 64 + m * 16 + lr + tap + hoff;
            int C = c0 * 4 + (lk >> 3);
            int cs = (C & ~7) | ((C ^ row) & 7);
            av[m] = *reinterpret_cast<const bf16x8*>(&As[row * 256 + cs * 8]);
        }
        #pragma unroll
        for (int n = 0; n < 4; ++n) {
            int nn = wc * 64 + n * 16 + lr;
            int cs = (lk >> 3) ^ ((nn >> 1) & 3);
            bv[n] = *reinterpret_cast<const bf16x8*>(&Bs[buf][nn * 32 + cs * 8]);
        }
        #pragma unroll
        for (int m = 0; m < 4; ++m)
            #pragma unroll
            for (int n = 0; n < 4; ++n)
                acc[m][n] = __builtin_amdgcn_mfma_f32_16x16x32_bf16(av[m], bv[n], acc[m][n], 0, 0, 0);
        __syncthreads();   // drain staged B + protect buffers
    }

    // ---- epilogue: bias + GELU + LN + bf16 write ----
    float bias_c[4], lng_c[4], lnb_c[4];
    #pragma unroll
    for (int n = 0; n < 4; ++n) {
        int col = wc * 64 + n * 16 + lr;
        bias_c[n] = bias[col];
        lng_c[n] = lng[col];
        lnb_c[n] = lnb[col];
    }
    #pragma unroll
    for (int m = 0; m < 4; ++m) {
        #pragma unroll
        for (int r = 0; r < 4; ++r) {
            float s = 0.0f, sq = 0.0f;
            #pragma unroll
            for (int n = 0; n < 4; ++n) {
                float v = acc[m][n][r] + bias_c[n];
                v = gelu_exact(v);
                acc[m][n][r] = v;
                s += v; sq += v * v;
            }
            s += __shfl_xor(s, 1);  sq += __shfl_xor(sq, 1);
            s += __shfl_xor(s, 2);  sq += __shfl_xor(sq, 2);
            s += __shfl_xor(s, 4);  sq += __shfl_xor(sq, 4);
            s += __shfl_xor(s, 8);  sq += __shfl_xor(sq, 8);
            if (lr == 0) {
                int rl = wr * 64 + m * 16 + quad * 4 + r;
                rs[rl][wc] = s;
                rq[rl][wc] = sq;
            }
        }
    }
    __syncthreads();
    #pragma unroll
    for (int m = 0; m < 4; ++m) {
        #pragma unroll
        for (int r = 0; r < 4; ++r) {
            int rl = wr * 64 + m * 16 + quad * 4 + r;
            float mean = (rs[rl][0] + rs[rl][1] + rs[rl][2] + rs[rl][3]) * (1.0f / 256.0f);
            float var = (rq[rl][0] + rq[rl][1] + rq[rl][2] + rq[rl][3]) * (1.0f / 256.0f) - mean * mean;
            float inv = rsqrtf(var + 1e-3f);
            int trow = tloc + rl;
            ushort_t* cp = ctx_out + ((size_t)b * PADROWS + PAD0 + trow) * CDIM;
            #pragma unroll
            for (int n = 0; n < 4; ++n) {
                int col = wc * 64 + n * 16 + lr;
                float y = (acc[m][n][r] - mean) * inv * lng_c[n] + lnb_c[n];
                cp[col] = f2bf(y);
            }
        }
    }
}

// ---------------- gates sliver ----------------
__global__ __launch_bounds__(256) void gates_kernel(const float* __restrict__ x,
                                                    const float* __restrict__ f_w,
                                                    const float* __restrict__ f_b,
                                                    float* __restrict__ gates) {
    __shared__ float fcol[256][4];
    int tid = threadIdx.x;
    #pragma unroll
    for (int j = 0; j < 4; ++j) fcol[tid][j] = f_w[(size_t)tid * 516 + 512 + j];
    __syncthreads();
    int w = tid >> 6, l = tid & 63;
    int t = blockIdx.x * 4 + w;
    float4 xv = ((const float4*)(x + (size_t)t * CDIM))[l];
    int c = l * 4;
    float a[4];
    #pragma unroll
    for (int j = 0; j < 4; ++j)
        a[j] = xv.x * fcol[c][j] + xv.y * fcol[c + 1][j] + xv.z * fcol[c + 2][j] + xv.w * fcol[c + 3][j];
    #pragma unroll
    for (int off = 32; off >= 1; off >>= 1)
        #pragma unroll
        for (int j = 0; j < 4; ++j) a[j] += __shfl_xor(a[j], off);
    if (l == 0) {
        #pragma unroll
        for (int j = 0; j < 4; ++j) gates[(size_t)t * 4 + j] = a[j] + f_b[512 + j];
    }
}

// ---------------- column mean over L (two stage), input bf16 padded ----------------
__global__ __launch_bounds__(256) void col_mean_partial(const ushort_t* __restrict__ ctx_pad,
                                                        float* __restrict__ partial) {
    int b = blockIdx.x, chunk = blockIdx.y, c = threadIdx.x;
    const ushort_t* base = ctx_pad + ((size_t)b * PADROWS + PAD0 + chunk * 256) * CDIM + c;
    float s = 0.0f;
    for (int r = 0; r < 256; ++r) s += bf2f(base[(size_t)r * CDIM]);
    partial[((size_t)b * 32 + chunk) * CDIM + c] = s;
}

__global__ __launch_bounds__(256) void col_mean_final(const float* __restrict__ partial,
                                                      float* __restrict__ meanv) {
    int b = blockIdx.x, c = threadIdx.x;
    float s = 0.0f;
    for (int i = 0; i < 32; ++i) s += partial[((size_t)b * 32 + i) * CDIM + c];
    meanv[b * CDIM + c] = s * (1.0f / (float)LSEQ);
}

// ---------------- A_bf = bf16(sum_l gate_l*ctx_l + meanv*g3) ----------------
__global__ __launch_bounds__(256) void finalize_A(
    const ushort_t* __restrict__ c0buf, const ushort_t* __restrict__ c1buf,
    const ushort_t* __restrict__ c2buf,
    const float* __restrict__ meanv, const float* __restrict__ gates,
    ushort_t* __restrict__ A_bf)
{
    int i = blockIdx.x * 256 + threadIdx.x;   // 8 channels per thread
    int t = i >> 5;
    int c8 = (i & 31) * 8;
    int b = t >> 13, tb = t & (LSEQ - 1);
    size_t pidx = ((size_t)b * PADROWS + PAD0 + tb) * CDIM + c8;
    const float* g = gates + (size_t)t * 4;
    float g0 = g[0], g1 = g[1], g2 = g[2], g3 = g[3];
    ushort4 a0 = *(const ushort4*)(c0buf + pidx);
    ushort4 a1 = *(const ushort4*)(c0buf + pidx + 4);
    ushort4 b0 = *(const ushort4*)(c1buf + pidx);
    ushort4 b1 = *(const ushort4*)(c1buf + pidx + 4);
    ushort4 d0 = *(const ushort4*)(c2buf + pidx);
    ushort4 d1 = *(const ushort4*)(c2buf + pidx + 4);
    const float* mv = meanv + b * CDIM + c8;
    ushort_t out[8];
    ushort_t va[8] = { a0.x, a0.y, a0.z, a0.w, a1.x, a1.y, a1.z, a1.w };
    ushort_t vb[8] = { b0.x, b0.y, b0.z, b0.w, b1.x, b1.y, b1.z, b1.w };
    ushort_t vd[8] = { d0.x, d0.y, d0.z, d0.w, d1.x, d1.y, d1.z, d1.w };
    #pragma unroll
    for (int j = 0; j < 8; ++j) {
        float v = bf2f(va[j]) * g0 + bf2f(vb[j]) * g1 + bf2f(vd[j]) * g2 + mv[j] * g3;
        out[j] = f2bf(v);
    }
    *(ushort4*)(A_bf + (size_t)t * CDIM + c8)     = make_ushort4(out[0], out[1], out[2], out[3]);
    *(ushort4*)(A_bf + (size_t)t * CDIM + c8 + 4) = make_ushort4(out[4], out[5], out[6], out[7]);
}

extern "C" void kernel_launch(void* const* d_in, const int* in_sizes, int n_in,
                              void* d_out, int out_size, void* d_ws, size_t ws_size,
                              hipStream_t stream) {
    const float* x      = (const float*)d_in[0];
    const float* f_w    = (const float*)d_in[1];
    const float* f_b    = (const float*)d_in[2];
    const float* h_w    = (const float*)d_in[3];
    const float* h_b    = (const float*)d_in[4];
    const float* proj_w = (const float*)d_in[5];
    const float* proj_b = (const float*)d_in[6];
    const float* conv_w[3] = { (const float*)d_in[7],  (const float*)d_in[11], (const float*)d_in[15] };
    const float* conv_b[3] = { (const float*)d_in[8],  (const float*)d_in[12], (const float*)d_in[16] };
    const float* ln_g[3]   = { (const float*)d_in[9],  (const float*)d_in[13], (const float*)d_in[17] };
    const float* ln_b[3]   = { (const float*)d_in[10], (const float*)d_in[14], (const float*)d_in[18] };

    const size_t MC = (size_t)MTOT * CDIM;
    const size_t PADC = (size_t)BATCH * PADROWS * CDIM;
    char* w = (char*)d_ws;
    ushort_t* x_bf  = (ushort_t*)w;  w += MC * 2;
    ushort_t* q_bf  = (ushort_t*)w;  w += MC * 2;
    ushort_t* ctxF  = (ushort_t*)w;  w += PADC * 2;
    ushort_t* ctx0  = (ushort_t*)w;  w += PADC * 2;
    ushort_t* ctx1  = (ushort_t*)w;  w += PADC * 2;
    ushort_t* ctx2  = (ushort_t*)w;  w += PADC * 2;
    float* gates    = (float*)w;     w += (size_t)MTOT * 4 * 4;
    float* partial  = (float*)w;     w += (size_t)8 * 32 * CDIM * 4;
    float* meanv    = (float*)w;     w += (size_t)8 * CDIM * 4;
    ushort_t* f_wT  = (ushort_t*)w;  w += (size_t)512 * 256 * 2;
    ushort_t* convT0 = (ushort_t*)w; w += (size_t)768 * 256 * 2;
    ushort_t* convT1 = (ushort_t*)w; w += (size_t)1280 * 256 * 2;
    ushort_t* convT2 = (ushort_t*)w; w += (size_t)1792 * 256 * 2;
    ushort_t* h_wT   = (ushort_t*)w; w += (size_t)256 * 256 * 2;
    ushort_t* proj_wT = (ushort_t*)w; w += (size_t)256 * 256 * 2;
    ushort_t* A_bf = x_bf;           // reuse (x_bf consumed after fea gemm)

    dim3 blk(256);
    dim3 t8(32, 8);

    // weight prep + x conversion
    cvt_f32_bf16<<<dim3(MC / 4 / 256), blk, 0, stream>>>(x, x_bf);
    transpose_cvt<<<dim3(8, 16), t8, 0, stream>>>(f_w, f_wT, 256, 512, 516, 0);
    transpose_cvt<<<dim3(24, 8), t8, 0, stream>>>(conv_w[0], convT0, 768, 256, 256, 0);
    transpose_cvt<<<dim3(40, 8), t8, 0, stream>>>(conv_w[1], convT1, 1280, 256, 256, 0);
    transpose_cvt<<<dim3(56, 8), t8, 0, stream>>>(conv_w[2], convT2, 1792, 256, 256, 0);
    transpose_cvt<<<dim3(8, 8), t8, 0, stream>>>(h_w, h_wT, 256, 256, 256, 0);
    transpose_cvt<<<dim3(8, 8), t8, 0, stream>>>(proj_w, proj_wT, 256, 256, 256, 0);
    zero_guards<<<dim3(128), blk, 0, stream>>>(ctxF);
    zero_guards<<<dim3(128), blk, 0, stream>>>(ctx0);
    zero_guards<<<dim3(128), blk, 0, stream>>>(ctx1);
    zero_guards<<<dim3(128), blk, 0, stream>>>(ctx2);

    // feature GEMM (q + ctx) and gates sliver
    gemm_bf16<1><<<dim3(4, 512), blk, 0, stream>>>(x_bf, f_wT, f_b,
        nullptr, q_bf, ctxF, 256);
    gates_kernel<<<dim3(MTOT / 4), blk, 0, stream>>>(x, f_w, f_b, gates);

    // three halo-LDS fused conv+GELU+LN levels
    conv_fused<<<dim3(512), dim3(512), 0, stream>>>(ctxF, convT0, conv_b[0],
        ln_g[0], ln_b[0], ctx0, 3, 768);
    conv_fused<<<dim3(512), dim3(512), 0, stream>>>(ctx0, convT1, conv_b[1],
        ln_g[1], ln_b[1], ctx1, 5, 1280);
    conv_fused<<<dim3(512), dim3(512), 0, stream>>>(ctx1, convT2, conv_b[2],
        ln_g[2], ln_b[2], ctx2, 7, 1792);

    // global context mean (final ctx is ctx2)
    col_mean_partial<<<dim3(BATCH, 32), blk, 0, stream>>>(ctx2, partial);
    col_mean_final<<<dim3(BATCH), blk, 0, stream>>>(partial, meanv);

    // combine levels: A_bf = bf16(sum gate_l*ctx_l + mean*g3)
    finalize_A<<<dim3(MTOT * 32 / 256), blk, 0, stream>>>(ctx0, ctx1, ctx2,
        meanv, gates, A_bf);

    // h GEMM with fused q .* (.) epilogue: q_bf <- bf16(q_bf * ctxh)
    gemm_bf16<2><<<dim3(2, 512), blk, 0, stream>>>(A_bf, h_wT, h_b,
        nullptr, q_bf, nullptr, 256);
    // final projection: qc @ proj_w -> d_out (fp32)
    gemm_bf16<0><<<dim3(2, 512), blk, 0, stream>>>(q_bf, proj_wT, proj_b,
        (float*)d_out, nullptr, nullptr, 256);
}

// Round 5
// 376.899 us; speedup vs baseline: 1.6112x; 1.1890x over previous
//
#include <hip/hip_runtime.h>
#include <math.h>

#define CDIM 256
#define LSEQ 8192
#define BATCH 8
#define MTOT (BATCH * LSEQ)
#define PADROWS 8208           // 8 + 8192 + 8 per batch
#define PAD0 8

typedef unsigned short ushort_t;
typedef unsigned int uint_t;

typedef __bf16 bf16x8 __attribute__((ext_vector_type(8)));
typedef float f32x4 __attribute__((ext_vector_type(4)));

__device__ __forceinline__ ushort_t f2bf(float f) {
    union { float f; uint_t u; } v; v.f = f;
    uint_t u = v.u;
    return (ushort_t)((u + 0x7FFFu + ((u >> 16) & 1u)) >> 16);  // RNE
}
__device__ __forceinline__ float bf2f(ushort_t h) {
    union { uint_t u; float f; } v; v.u = ((uint_t)h) << 16;
    return v.f;
}
__device__ __forceinline__ float gelu_exact(float x) {
    return 0.5f * x * (1.0f + erff(x * 0.70710678118654752440f));
}

// async global(16B/lane) -> LDS (wave-uniform base + lane*16)
__device__ __forceinline__ void gload16(const ushort_t* g, ushort_t* lds) {
    __builtin_amdgcn_global_load_lds(
        reinterpret_cast<__attribute__((address_space(1))) uint_t*>(
            reinterpret_cast<uintptr_t>(g)),
        reinterpret_cast<__attribute__((address_space(3))) uint_t*>(
            reinterpret_cast<uintptr_t>(lds)),
        16, 0, 0);
}

// ---------------- fp32 -> bf16 convert ----------------
__global__ __launch_bounds__(256) void cvt_f32_bf16(const float* __restrict__ in,
                                                    ushort_t* __restrict__ out) {
    int i = blockIdx.x * 256 + threadIdx.x;
    float4 v = ((const float4*)in)[i];
    ushort4 o = { f2bf(v.x), f2bf(v.y), f2bf(v.z), f2bf(v.w) };
    ((ushort4*)out)[i] = o;
}

// ---------------- transpose + convert: out[n*K+k] = bf16(in[k*ldin+col0+n]) ----------------
__global__ __launch_bounds__(256) void transpose_cvt(const float* __restrict__ in,
                                                     ushort_t* __restrict__ out,
                                                     int K, int N, int ldin, int col0) {
    __shared__ float t[32][33];
    int k0 = blockIdx.x * 32, n0 = blockIdx.y * 32;
    int tx = threadIdx.x, ty = threadIdx.y;   // (32,8)
    #pragma unroll
    for (int i = 0; i < 4; i++) {
        int k = k0 + ty + i * 8;
        t[ty + i * 8][tx] = in[(size_t)k * ldin + col0 + n0 + tx];
    }
    __syncthreads();
    #pragma unroll
    for (int i = 0; i < 4; i++) {
        int n = n0 + ty + i * 8;
        out[(size_t)n * K + k0 + tx] = f2bf(t[tx][ty + i * 8]);
    }
}

// ---------------- zero the guard bands of a ctx_pad buffer ----------------
__global__ __launch_bounds__(256) void zero_guards(ushort_t* __restrict__ ctx_pad) {
    int i = blockIdx.x * 256 + threadIdx.x;   // 8*16*256 = 32768
    int c = i & 255;
    int r = (i >> 8) & 15;
    int b = i >> 12;
    int row = b * PADROWS + ((r < 8) ? r : (PADROWS - 16 + r));
    ctx_pad[(size_t)row * CDIM + c] = 0;
}

// ---------------- generic MFMA GEMM (m97 structure): 128x128 tile ----------------
// MODE 0: C[row*256+col] = acc + bias  (fp32 out)
// MODE 1: fea: col<256 -> q_bf(bf16) ; col>=256 -> ctx_pad (padded rows, bf16)
// MODE 2: qc in-place: q_out[idx] = bf16(bf2f(q_out[idx]) * (acc+bias))
template <int MODE>
__global__ __launch_bounds__(256) void gemm_bf16(
    const ushort_t* __restrict__ A, const ushort_t* __restrict__ BT,
    const float* __restrict__ bias,
    float* __restrict__ C, ushort_t* __restrict__ q_out, ushort_t* __restrict__ ctx_pad,
    int Ktot)
{
    __shared__ __align__(16) ushort_t As[128 * 32];
    __shared__ __align__(16) ushort_t Bs[128 * 32];
    int tid = threadIdx.x;
    int w = tid >> 6, l = tid & 63;
    int bn = blockIdx.x * 128;
    int by = blockIdx.y;
    long arow0 = (long)by * 128;
    int crow0 = by * 128;

    int wr = w >> 1, wc = w & 1;
    int lr = l & 15, lk = (l >> 4) * 8;
    int sr = l >> 2;
    int sc = (l & 3) * 8;

    f32x4 acc[4][4] = {};

    int nsteps = Ktot >> 5;
    for (int kt = 0; kt < nsteps; ++kt) {
        int k0 = kt << 5;
        #pragma unroll
        for (int jj = 0; jj < 2; ++jj) {
            int j = w * 2 + jj;
            int r = j * 16 + sr;
            gload16(A + (arow0 + r) * CDIM + (k0 + sc), &As[j * 512]);
            gload16(BT + (long)(bn + r) * Ktot + (k0 + sc), &Bs[j * 512]);
        }
        __syncthreads();
        bf16x8 av[4], bv[4];
        #pragma unroll
        for (int m = 0; m < 4; ++m)
            av[m] = *reinterpret_cast<const bf16x8*>(&As[(wr * 64 + m * 16 + lr) * 32 + lk]);
        #pragma unroll
        for (int n = 0; n < 4; ++n)
            bv[n] = *reinterpret_cast<const bf16x8*>(&Bs[(wc * 64 + n * 16 + lr) * 32 + lk]);
        #pragma unroll
        for (int m = 0; m < 4; ++m)
            #pragma unroll
            for (int n = 0; n < 4; ++n)
                acc[m][n] = __builtin_amdgcn_mfma_f32_16x16x32_bf16(av[m], bv[n], acc[m][n], 0, 0, 0);
        __syncthreads();
    }

    int rbase = (l >> 4) * 4;
    #pragma unroll
    for (int n = 0; n < 4; ++n) {
        int col = bn + wc * 64 + n * 16 + lr;
        float bia = bias[col];
        #pragma unroll
        for (int m = 0; m < 4; ++m) {
            int rowb = crow0 + wr * 64 + m * 16 + rbase;
            #pragma unroll
            for (int r = 0; r < 4; ++r) {
                float v = acc[m][n][r] + bia;
                int row = rowb + r;
                if (MODE == 0) {
                    C[(size_t)row * CDIM + col] = v;
                } else if (MODE == 1) {
                    if (col < CDIM) {
                        q_out[(size_t)row * CDIM + col] = f2bf(v);
                    } else {
                        int bb = row >> 13, tb = row & (LSEQ - 1);
                        ctx_pad[((size_t)bb * PADROWS + PAD0 + tb) * CDIM + (col - CDIM)] = f2bf(v);
                    }
                } else {
                    size_t idx = (size_t)row * CDIM + col;
                    q_out[idx] = f2bf(bf2f(q_out[idx]) * v);
                }
            }
        }
    }
}

// ---- staging helpers for conv_fused ----
// A chunk: 144 rows x 32 ch, write-side swizzle cg = cp ^ (row&3)
__device__ __forceinline__ void stageA_chunk(const ushort_t* Arow0, int cc,
                                             ushort_t* asb, int tid, int w) {
    int o = tid;                  // 0..511
    int row = o >> 2, cp = o & 3;
    int cg = cp ^ (row & 3);
    gload16(Arow0 + (size_t)row * CDIM + cc * 32 + cg * 8, asb + (size_t)(w * 64) * 8);
    if (tid < 64) {               // wave 0 covers rows 128..143
        int o2 = 512 + tid;
        int row2 = o2 >> 2, cp2 = o2 & 3;
        int cg2 = cp2 ^ (row2 & 3);
        gload16(Arow0 + (size_t)row2 * CDIM + cc * 32 + cg2 * 8, asb + (size_t)512 * 8);
    }
}
// B chunk: 256 rows x 32 ch, write-side swizzle cg = cp ^ ((n>>1)&3)
__device__ __forceinline__ void stageB_chunk(const ushort_t* BT, int Ktot, int koffB,
                                             ushort_t* bsb, int tid, int w) {
    #pragma unroll
    for (int i = 0; i < 2; ++i) {
        int o = tid + i * 512;
        int n = o >> 2, cp = o & 3;
        int cg = cp ^ ((n >> 1) & 3);
        gload16(BT + (size_t)n * Ktot + koffB + cg * 8, bsb + (size_t)(w * 64 + i * 512) * 8);
    }
}

// ---------------- fused conv: BM=128, BN=256, 512 thr, 2 blocks/CU ----------------
// A staged per 32-ch chunk (144 rows, double-buffered, 18KB); B chunks double-
// buffered (32KB). Loop (chunk outer, tap inner). Epilogue: bias+GELU+LN -> bf16.
__global__ __launch_bounds__(512, 4) void conv_fused(
    const ushort_t* __restrict__ A, const ushort_t* __restrict__ BT,
    const float* __restrict__ bias,
    const float* __restrict__ lng, const float* __restrict__ lnb,
    ushort_t* __restrict__ ctx_out, int KW, int Ktot)
{
    __shared__ __align__(16) ushort_t As2[2][144 * 32];  // 18432 B
    __shared__ __align__(16) ushort_t Bs[2][256 * 32];   // 32768 B

    int tid = threadIdx.x;
    int w = tid >> 6, l = tid & 63;
    int by = blockIdx.x;              // 512 blocks: 64 tiles/batch
    int b = by >> 6;
    int tloc = (by & 63) << 7;
    const ushort_t* Arow0 = A + ((size_t)b * PADROWS + PAD0 + tloc - 8) * CDIM;

    int wr = w >> 2;                  // 0..1 : rows wr*64..+63
    int wc = w & 3;                   // 0..3 : cols wc*64..+63
    int lr = l & 15;
    int quad = l >> 4;

    int P = KW >> 1;
    int hoff = 8 - P;
    f32x4 acc[4][4] = {};

    stageA_chunk(Arow0, 0, As2[0], tid, w);
    stageB_chunk(BT, Ktot, 0, Bs[0], tid, w);
    __syncthreads();

    int nIt = KW * 8;
    int it = 0;
    for (int c = 0; c < 8; ++c) {
        for (int tap = 0; tap < KW; ++tap, ++it) {
            if (tap == 0 && c < 7)
                stageA_chunk(Arow0, c + 1, As2[(c + 1) & 1], tid, w);
            if (it + 1 < nIt) {
                int tapn = tap + 1, cn = c;
                if (tapn == KW) { tapn = 0; cn = c + 1; }
                stageB_chunk(BT, Ktot, tapn * 256 + cn * 32, Bs[(it + 1) & 1], tid, w);
            }
            const ushort_t* asb = As2[c & 1];
            const ushort_t* bsb = Bs[it & 1];
            bf16x8 av[4], bv[4];
            #pragma unroll
            for (int m = 0; m < 4; ++m) {
                int row = wr * 64 + m * 16 + lr + tap + hoff;
                int cs = quad ^ (row & 3);
                av[m] = *reinterpret_cast<const bf16x8*>(&asb[row * 32 + cs * 8]);
            }
            #pragma unroll
            for (int n = 0; n < 4; ++n) {
                int nn = wc * 64 + n * 16 + lr;
                int cs = quad ^ ((nn >> 1) & 3);
                bv[n] = *reinterpret_cast<const bf16x8*>(&bsb[nn * 32 + cs * 8]);
            }
            #pragma unroll
            for (int m = 0; m < 4; ++m)
                #pragma unroll
                for (int n = 0; n < 4; ++n)
                    acc[m][n] = __builtin_amdgcn_mfma_f32_16x16x32_bf16(av[m], bv[n], acc[m][n], 0, 0, 0);
            __syncthreads();
        }
    }

    // ---- epilogue: bias + GELU + LN + bf16 write (stats overlay Bs[0]) ----
    float* rs = (float*)&Bs[0][0];      // [128][4]
    float* rq = rs + 512;               // [128][4]
    float bias_c[4], lng_c[4], lnb_c[4];
    #pragma unroll
    for (int n = 0; n < 4; ++n) {
        int col = wc * 64 + n * 16 + lr;
        bias_c[n] = bias[col];
        lng_c[n] = lng[col];
        lnb_c[n] = lnb[col];
    }
    #pragma unroll
    for (int m = 0; m < 4; ++m) {
        #pragma unroll
        for (int r = 0; r < 4; ++r) {
            float s = 0.0f, sq = 0.0f;
            #pragma unroll
            for (int n = 0; n < 4; ++n) {
                float v = acc[m][n][r] + bias_c[n];
                v = gelu_exact(v);
                acc[m][n][r] = v;
                s += v; sq += v * v;
            }
            s += __shfl_xor(s, 1);  sq += __shfl_xor(sq, 1);
            s += __shfl_xor(s, 2);  sq += __shfl_xor(sq, 2);
            s += __shfl_xor(s, 4);  sq += __shfl_xor(sq, 4);
            s += __shfl_xor(s, 8);  sq += __shfl_xor(sq, 8);
            if (lr == 0) {
                int rl = wr * 64 + m * 16 + quad * 4 + r;
                rs[rl * 4 + wc] = s;
                rq[rl * 4 + wc] = sq;
            }
        }
    }
    __syncthreads();
    #pragma unroll
    for (int m = 0; m < 4; ++m) {
        #pragma unroll
        for (int r = 0; r < 4; ++r) {
            int rl = wr * 64 + m * 16 + quad * 4 + r;
            float mean = (rs[rl * 4] + rs[rl * 4 + 1] + rs[rl * 4 + 2] + rs[rl * 4 + 3]) * (1.0f / 256.0f);
            float var = (rq[rl * 4] + rq[rl * 4 + 1] + rq[rl * 4 + 2] + rq[rl * 4 + 3]) * (1.0f / 256.0f) - mean * mean;
            float inv = rsqrtf(var + 1e-3f);
            int trow = tloc + rl;
            ushort_t* cp = ctx_out + ((size_t)b * PADROWS + PAD0 + trow) * CDIM;
            #pragma unroll
            for (int n = 0; n < 4; ++n) {
                int col = wc * 64 + n * 16 + lr;
                float y = (acc[m][n][r] - mean) * inv * lng_c[n] + lnb_c[n];
                cp[col] = f2bf(y);
            }
        }
    }
}

// ---------------- gates sliver ----------------
__global__ __launch_bounds__(256) void gates_kernel(const float* __restrict__ x,
                                                    const float* __restrict__ f_w,
                                                    const float* __restrict__ f_b,
                                                    float* __restrict__ gates) {
    __shared__ float fcol[256][4];
    int tid = threadIdx.x;
    #pragma unroll
    for (int j = 0; j < 4; ++j) fcol[tid][j] = f_w[(size_t)tid * 516 + 512 + j];
    __syncthreads();
    int w = tid >> 6, l = tid & 63;
    int t = blockIdx.x * 4 + w;
    float4 xv = ((const float4*)(x + (size_t)t * CDIM))[l];
    int c = l * 4;
    float a[4];
    #pragma unroll
    for (int j = 0; j < 4; ++j)
        a[j] = xv.x * fcol[c][j] + xv.y * fcol[c + 1][j] + xv.z * fcol[c + 2][j] + xv.w * fcol[c + 3][j];
    #pragma unroll
    for (int off = 32; off >= 1; off >>= 1)
        #pragma unroll
        for (int j = 0; j < 4; ++j) a[j] += __shfl_xor(a[j], off);
    if (l == 0) {
        #pragma unroll
        for (int j = 0; j < 4; ++j) gates[(size_t)t * 4 + j] = a[j] + f_b[512 + j];
    }
}

// ---------------- column mean over L (two stage), input bf16 padded ----------------
__global__ __launch_bounds__(256) void col_mean_partial(const ushort_t* __restrict__ ctx_pad,
                                                        float* __restrict__ partial) {
    int b = blockIdx.x, chunk = blockIdx.y, c = threadIdx.x;
    const ushort_t* base = ctx_pad + ((size_t)b * PADROWS + PAD0 + chunk * 256) * CDIM + c;
    float s = 0.0f;
    for (int r = 0; r < 256; ++r) s += bf2f(base[(size_t)r * CDIM]);
    partial[((size_t)b * 32 + chunk) * CDIM + c] = s;
}

__global__ __launch_bounds__(256) void col_mean_final(const float* __restrict__ partial,
                                                      float* __restrict__ meanv) {
    int b = blockIdx.x, c = threadIdx.x;
    float s = 0.0f;
    for (int i = 0; i < 32; ++i) s += partial[((size_t)b * 32 + i) * CDIM + c];
    meanv[b * CDIM + c] = s * (1.0f / (float)LSEQ);
}

// ---------------- A_bf = bf16(sum_l gate_l*ctx_l + meanv*g3) ----------------
__global__ __launch_bounds__(256) void finalize_A(
    const ushort_t* __restrict__ c0buf, const ushort_t* __restrict__ c1buf,
    const ushort_t* __restrict__ c2buf,
    const float* __restrict__ meanv, const float* __restrict__ gates,
    ushort_t* __restrict__ A_bf)
{
    int i = blockIdx.x * 256 + threadIdx.x;   // 8 channels per thread
    int t = i >> 5;
    int c8 = (i & 31) * 8;
    int b = t >> 13, tb = t & (LSEQ - 1);
    size_t pidx = ((size_t)b * PADROWS + PAD0 + tb) * CDIM + c8;
    const float* g = gates + (size_t)t * 4;
    float g0 = g[0], g1 = g[1], g2 = g[2], g3 = g[3];
    ushort4 a0 = *(const ushort4*)(c0buf + pidx);
    ushort4 a1 = *(const ushort4*)(c0buf + pidx + 4);
    ushort4 b0 = *(const ushort4*)(c1buf + pidx);
    ushort4 b1 = *(const ushort4*)(c1buf + pidx + 4);
    ushort4 d0 = *(const ushort4*)(c2buf + pidx);
    ushort4 d1 = *(const ushort4*)(c2buf + pidx + 4);
    const float* mv = meanv + b * CDIM + c8;
    ushort_t out[8];
    ushort_t va[8] = { a0.x, a0.y, a0.z, a0.w, a1.x, a1.y, a1.z, a1.w };
    ushort_t vb[8] = { b0.x, b0.y, b0.z, b0.w, b1.x, b1.y, b1.z, b1.w };
    ushort_t vd[8] = { d0.x, d0.y, d0.z, d0.w, d1.x, d1.y, d1.z, d1.w };
    #pragma unroll
    for (int j = 0; j < 8; ++j) {
        float v = bf2f(va[j]) * g0 + bf2f(vb[j]) * g1 + bf2f(vd[j]) * g2 + mv[j] * g3;
        out[j] = f2bf(v);
    }
    *(ushort4*)(A_bf + (size_t)t * CDIM + c8)     = make_ushort4(out[0], out[1], out[2], out[3]);
    *(ushort4*)(A_bf + (size_t)t * CDIM + c8 + 4) = make_ushort4(out[4], out[5], out[6], out[7]);
}

extern "C" void kernel_launch(void* const* d_in, const int* in_sizes, int n_in,
                              void* d_out, int out_size, void* d_ws, size_t ws_size,
                              hipStream_t stream) {
    const float* x      = (const float*)d_in[0];
    const float* f_w    = (const float*)d_in[1];
    const float* f_b    = (const float*)d_in[2];
    const float* h_w    = (const float*)d_in[3];
    const float* h_b    = (const float*)d_in[4];
    const float* proj_w = (const float*)d_in[5];
    const float* proj_b = (const float*)d_in[6];
    const float* conv_w[3] = { (const float*)d_in[7],  (const float*)d_in[11], (const float*)d_in[15] };
    const float* conv_b[3] = { (const float*)d_in[8],  (const float*)d_in[12], (const float*)d_in[16] };
    const float* ln_g[3]   = { (const float*)d_in[9],  (const float*)d_in[13], (const float*)d_in[17] };
    const float* ln_b[3]   = { (const float*)d_in[10], (const float*)d_in[14], (const float*)d_in[18] };

    const size_t MC = (size_t)MTOT * CDIM;
    const size_t PADC = (size_t)BATCH * PADROWS * CDIM;
    char* w = (char*)d_ws;
    ushort_t* x_bf  = (ushort_t*)w;  w += MC * 2;
    ushort_t* q_bf  = (ushort_t*)w;  w += MC * 2;
    ushort_t* ctxF  = (ushort_t*)w;  w += PADC * 2;
    ushort_t* ctx0  = (ushort_t*)w;  w += PADC * 2;
    ushort_t* ctx1  = (ushort_t*)w;  w += PADC * 2;
    ushort_t* ctx2  = (ushort_t*)w;  w += PADC * 2;
    float* gates    = (float*)w;     w += (size_t)MTOT * 4 * 4;
    float* partial  = (float*)w;     w += (size_t)8 * 32 * CDIM * 4;
    float* meanv    = (float*)w;     w += (size_t)8 * CDIM * 4;
    ushort_t* f_wT  = (ushort_t*)w;  w += (size_t)512 * 256 * 2;
    ushort_t* convT0 = (ushort_t*)w; w += (size_t)768 * 256 * 2;
    ushort_t* convT1 = (ushort_t*)w; w += (size_t)1280 * 256 * 2;
    ushort_t* convT2 = (ushort_t*)w; w += (size_t)1792 * 256 * 2;
    ushort_t* h_wT   = (ushort_t*)w; w += (size_t)256 * 256 * 2;
    ushort_t* proj_wT = (ushort_t*)w; w += (size_t)256 * 256 * 2;
    ushort_t* A_bf = x_bf;           // reuse (x_bf consumed after fea gemm)

    dim3 blk(256);
    dim3 t8(32, 8);

    // weight prep + x conversion
    cvt_f32_bf16<<<dim3(MC / 4 / 256), blk, 0, stream>>>(x, x_bf);
    transpose_cvt<<<dim3(8, 16), t8, 0, stream>>>(f_w, f_wT, 256, 512, 516, 0);
    transpose_cvt<<<dim3(24, 8), t8, 0, stream>>>(conv_w[0], convT0, 768, 256, 256, 0);
    transpose_cvt<<<dim3(40, 8), t8, 0, stream>>>(conv_w[1], convT1, 1280, 256, 256, 0);
    transpose_cvt<<<dim3(56, 8), t8, 0, stream>>>(conv_w[2], convT2, 1792, 256, 256, 0);
    transpose_cvt<<<dim3(8, 8), t8, 0, stream>>>(h_w, h_wT, 256, 256, 256, 0);
    transpose_cvt<<<dim3(8, 8), t8, 0, stream>>>(proj_w, proj_wT, 256, 256, 256, 0);
    zero_guards<<<dim3(128), blk, 0, stream>>>(ctxF);
    zero_guards<<<dim3(128), blk, 0, stream>>>(ctx0);
    zero_guards<<<dim3(128), blk, 0, stream>>>(ctx1);
    zero_guards<<<dim3(128), blk, 0, stream>>>(ctx2);

    // feature GEMM (q + ctx) and gates sliver
    gemm_bf16<1><<<dim3(4, 512), blk, 0, stream>>>(x_bf, f_wT, f_b,
        nullptr, q_bf, ctxF, 256);
    gates_kernel<<<dim3(MTOT / 4), blk, 0, stream>>>(x, f_w, f_b, gates);

    // three fused conv+GELU+LN levels
    conv_fused<<<dim3(512), dim3(512), 0, stream>>>(ctxF, convT0, conv_b[0],
        ln_g[0], ln_b[0], ctx0, 3, 768);
    conv_fused<<<dim3(512), dim3(512), 0, stream>>>(ctx0, convT1, conv_b[1],
        ln_g[1], ln_b[1], ctx1, 5, 1280);
    conv_fused<<<dim3(512), dim3(512), 0, stream>>>(ctx1, convT2, conv_b[2],
        ln_g[2], ln_b[2], ctx2, 7, 1792);

    // global context mean (final ctx is ctx2)
    col_mean_partial<<<dim3(BATCH, 32), blk, 0, stream>>>(ctx2, partial);
    col_mean_final<<<dim3(BATCH), blk, 0, stream>>>(partial, meanv);

    // combine levels: A_bf = bf16(sum gate_l*ctx_l + mean*g3)
    finalize_A<<<dim3(MTOT * 32 / 256), blk, 0, stream>>>(ctx0, ctx1, ctx2,
        meanv, gates, A_bf);

    // h GEMM with fused q .* (.) epilogue: q_bf <- bf16(q_bf * ctxh)
    gemm_bf16<2><<<dim3(2, 512), blk, 0, stream>>>(A_bf, h_wT, h_b,
        nullptr, q_bf, nullptr, 256);
    // final projection: qc @ proj_w -> d_out (fp32)
    gemm_bf16<0><<<dim3(2, 512), blk, 0, stream>>>(q_bf, proj_wT, proj_b,
        (float*)d_out, nullptr, nullptr, 256);
}